// Round 11
// baseline (772.884 us; speedup 1.0000x reference)
//
#include <hip/hip_runtime.h>
#include <hip/hip_bf16.h>

#define EPS 1e-5f
#define INV_VRF 4.4194173824159220e-02f  // 2/sqrt(2048)

#define NB 32
#define NP 2048
#define NI 4096
#define ND 64
#define NL 256

#define ATTN_OFF 32L
#define OUT_OFF  268435488L  // 32 + 32*2048*4096

typedef __attribute__((ext_vector_type(4))) float vf4;
typedef __attribute__((ext_vector_type(8))) short vs8;

__device__ __forceinline__ unsigned short f2bf(float f) {
  unsigned int u = __float_as_uint(f);
  unsigned int r = (u + 0x7FFFu + ((u >> 16) & 1u)) >> 16;
  return (unsigned short)r;
}

// permute k-index d (0..63) into MFMA-fragment element order, so a frag for
// (kk, g) is the contiguous 16B at element [kk*32 + g*8 .. +8).
__device__ __forceinline__ int kperm(int d) {
  int dd = d & 31;
  return (d & 32) + (((dd & 15) >> 2) << 3) + ((dd >> 4) << 2) + (dd & 3);
}

// ---------------- K1: qm = lrelu( lrelu(LN(s*qw)) @ qw2 ), bf16 (permuted cols) ----------------
__global__ __launch_bounds__(256) void k_qm(
    const float* __restrict__ pathway, const float* __restrict__ qw,
    const float* __restrict__ qw2, const float* __restrict__ q_g,
    const float* __restrict__ q_b, unsigned short* __restrict__ qm)
{
  __shared__ float qw2s[64 * 64];
  int tid = threadIdx.x, lane = tid & 63, w = tid >> 6;
  for (int idx = tid; idx < 4096; idx += 256) qw2s[idx] = qw2[idx];
  float qwv = qw[lane], qg = q_g[lane], qb = q_b[lane];
  float s1 = qwv, s2 = qwv * qwv;
  #pragma unroll
  for (int m = 32; m; m >>= 1) { s1 += __shfl_xor(s1, m); s2 += __shfl_xor(s2, m); }
  float mq = s1 * (1.f / 64.f), vq = s2 * (1.f / 64.f) - mq * mq;
  float qc = qwv - mq;
  int pdst = kperm(lane);
  __syncthreads();
  long base = (long)blockIdx.x * 32 + w * 8;
  for (int r = 0; r < 8; ++r) {
    long row = base + r;
    float s = pathway[row];
    float alpha = s * rsqrtf(s * s * vq + EPS);
    float t = alpha * qc * qg + qb;
    t = t >= 0.f ? t : 0.2f * t;
    float acc = 0.f;
    #pragma unroll
    for (int h = 0; h < 64; ++h) acc += __shfl(t, h) * qw2s[h * 64 + lane];
    acc = acc >= 0.f ? acc : 0.2f * acc;
    qm[row * 64 + pdst] = f2bf(acc);
  }
}

// ---------------- K2: km = LN(img_t@kw) bf16 (permuted cols) ; vm = lrelu(LN(img_t@vw))@vw2 ----------------
__global__ __launch_bounds__(256) void k_kmvm(
    const float* __restrict__ img, const float* __restrict__ kw,
    const float* __restrict__ vw, const float* __restrict__ vw2,
    const float* __restrict__ k_g, const float* __restrict__ k_b,
    const float* __restrict__ v_g, const float* __restrict__ v_b,
    unsigned short* __restrict__ km, float* __restrict__ vm)
{
  int tid = threadIdx.x, lane = tid & 63, w = tid >> 6;
  long row = (long)blockIdx.x * 4 + w;      // b*4096 + i
  int b = (int)(row >> 12), i = (int)(row & 4095);
  const float* ib = img + (long)b * 4 * 4096 + i;
  float xv = (lane < 4) ? ib[lane * 4096] : 0.f;
  float x0 = __shfl(xv, 0), x1 = __shfl(xv, 1), x2 = __shfl(xv, 2), x3 = __shfl(xv, 3);
  int d = lane;
  float kp = x0 * kw[d] + x1 * kw[64 + d] + x2 * kw[128 + d] + x3 * kw[192 + d];
  float vp = x0 * vw[d] + x1 * vw[64 + d] + x2 * vw[128 + d] + x3 * vw[192 + d];
  float a1 = kp, a2 = kp * kp, a3 = vp, a4 = vp * vp;
  #pragma unroll
  for (int m = 32; m; m >>= 1) {
    a1 += __shfl_xor(a1, m); a2 += __shfl_xor(a2, m);
    a3 += __shfl_xor(a3, m); a4 += __shfl_xor(a4, m);
  }
  float mk = a1 * (1.f / 64.f), vk = a2 * (1.f / 64.f) - mk * mk;
  float mv = a3 * (1.f / 64.f), vv = a4 * (1.f / 64.f) - mv * mv;
  float kmv = (kp - mk) * rsqrtf(vk + EPS) * k_g[d] + k_b[d];
  km[row * 64 + kperm(d)] = f2bf(kmv);
  float y = (vp - mv) * rsqrtf(vv + EPS) * v_g[d] + v_b[d];
  y = y >= 0.f ? y : 0.2f * y;
  float pv = y * vw2[d];
  #pragma unroll
  for (int m = 32; m; m >>= 1) pv += __shfl_xor(pv, m);
  if (lane == 0) vm[row] = pv;
}

// ---------------- K3: attn = softsign(relu(qm@km^T)/vrf) -> d_out ; out = attn@vm ----------------
// R2 structure; cache-policy experiment: PLAIN full-line stores (L2 writeback aggregation)
// + NON-TEMPORAL km/vm loads (keep the read stream from thrashing L2).
__global__ __launch_bounds__(256) void k_attn(
    const unsigned short* __restrict__ qm, const unsigned short* __restrict__ km,
    const float* __restrict__ vm, float* __restrict__ dout)
{
  __shared__ __align__(16) float tr_s[4][16 * 128];  // per-wave 16x128 f32, f4-XOR swizzled
  int tid = threadIdx.x, lane = tid & 63, w = tid >> 6;
  int g = lane >> 4, c = lane & 15;
  // XCD swizzle: blocks sharing b land on one XCD (1024 = 8 xcd * 128)
  int bid = blockIdx.x;
  int lbid = (bid & 7) * 128 + (bid >> 3);
  int b = lbid >> 5, pt = lbid & 31;
  long p_base = (long)b * NP + pt * 64;
  int prow = w * 16;

  // A fragments: rows p_base+prow+c, permuted element order -> one vs8 load per half
  const unsigned short* qrow = qm + (p_base + prow + c) * 64;
  vs8 afr0 = *(const vs8*)(qrow + g * 8);
  vs8 afr1 = *(const vs8*)(qrow + 32 + g * 8);

  const unsigned short* kb = km + (long)b * NI * 64;
  const float* vmb = vm + (long)b * NI;
  float* trw = tr_s[w];
  float* outbase = dout + ATTN_OFF + (p_base + prow) * (long)NI;
  float oacc[4] = {0.f, 0.f, 0.f, 0.f};

  for (int s = 0; s < 32; ++s) {
    int i0 = s * 128;
    vf4 acc[8];
    #pragma unroll
    for (int nt = 0; nt < 8; ++nt) acc[nt] = (vf4){0.f, 0.f, 0.f, 0.f};
    #pragma unroll
    for (int nt = 0; nt < 8; ++nt) {
      const unsigned short* krow = kb + (long)(i0 + nt * 16 + c) * 64;
      vs8 b0 = __builtin_nontemporal_load((const vs8*)(krow + g * 8));
      vs8 b1 = __builtin_nontemporal_load((const vs8*)(krow + 32 + g * 8));
      acc[nt] = __builtin_amdgcn_mfma_f32_16x16x32_bf16(afr0, b0, acc[nt], 0, 0, 0);
      acc[nt] = __builtin_amdgcn_mfma_f32_16x16x32_bf16(afr1, b1, acc[nt], 0, 0, 0);
    }
    // softsign + transpose write (XOR-swizzled f4 slots)
    #pragma unroll
    for (int nt = 0; nt < 8; ++nt) {
      #pragma unroll
      for (int r = 0; r < 4; ++r) {
        float x = fmaxf(acc[nt][r], 0.f) * INV_VRF;
        float y = x * __builtin_amdgcn_rcpf(x + 0.5f);
        int row = g * 4 + r;                 // 0..15
        int f4 = (nt * 4 + (c >> 2)) ^ row;  // 0..31, low-4-bit XOR
        trw[row * 128 + f4 * 4 + (c & 3)] = y;
      }
    }
    // transpose read + coalesced PLAIN stores (full 64B-line coverage -> writeback aggregation)
    #pragma unroll
    for (int pass = 0; pass < 2; ++pass) {
      vf4 vmv = __builtin_nontemporal_load((const vf4*)(vmb + i0 + pass * 64 + c * 4));
      #pragma unroll
      for (int j = 0; j < 4; ++j) {
        int row = j * 4 + g;
        int f4 = (pass * 16 + c) ^ row;
        vf4 yv = *(const vf4*)&trw[row * 128 + f4 * 4];
        *(vf4*)(outbase + (long)row * NI + i0 + pass * 64 + c * 4) = yv;
        oacc[j] += yv[0] * vmv[0] + yv[1] * vmv[1] + yv[2] * vmv[2] + yv[3] * vmv[3];
      }
    }
  }
  // reduce oacc over the 16 c-lanes within each g-group
  #pragma unroll
  for (int m = 1; m <= 8; m <<= 1) {
    #pragma unroll
    for (int j = 0; j < 4; ++j) oacc[j] += __shfl_xor(oacc[j], m);
  }
  if (c == 0) {
    #pragma unroll
    for (int j = 0; j < 4; ++j)
      dout[OUT_OFF + p_base + prow + j * 4 + g] = oacc[j];
  }
}

// ---------------- K4: classifier head ----------------
__global__ __launch_bounds__(256) void k_head(
    const float* __restrict__ n1_g, const float* __restrict__ n1_b,
    const float* __restrict__ n2_g, const float* __restrict__ n2_b,
    const float* __restrict__ w1, const float* __restrict__ b1,
    const float* __restrict__ w2, const float* __restrict__ b2,
    float* __restrict__ dout)
{
  int tid = threadIdx.x, lane = tid & 63, w = tid >> 6;
  int b = blockIdx.x;
  __shared__ float h1s[2048];
  __shared__ float red[8];
  const float* orow = dout + OUT_OFF + (long)b * NP;
  float vals[8];
  float s1 = 0.f, s2 = 0.f;
  #pragma unroll
  for (int j = 0; j < 8; ++j) {
    float v = orow[j * 256 + tid];
    vals[j] = v; s1 += v; s2 += v * v;
  }
  #pragma unroll
  for (int m = 32; m; m >>= 1) { s1 += __shfl_xor(s1, m); s2 += __shfl_xor(s2, m); }
  if (lane == 0) { red[w] = s1; red[4 + w] = s2; }
  __syncthreads();
  float S1 = red[0] + red[1] + red[2] + red[3];
  float S2 = red[4] + red[5] + red[6] + red[7];
  float mean = S1 * (1.f / 2048.f);
  float var = S2 * (1.f / 2048.f) - mean * mean;
  float rs = rsqrtf(var + EPS);
  __syncthreads();
  #pragma unroll
  for (int j = 0; j < 8; ++j) {
    int p = j * 256 + tid;
    float h = (vals[j] - mean) * rs * n1_g[p] + n1_b[p];
    h = h >= 0.f ? h : 0.2f * h;
    h1s[p] = h;
  }
  __syncthreads();
  float acc = b1[tid];
  const float* wr = w1 + (long)tid * 2048;
  for (int qq = 0; qq < 2048; qq += 4) {
    float4 wv = *(const float4*)(wr + qq);
    acc += wv.x * h1s[qq] + wv.y * h1s[qq + 1] + wv.z * h1s[qq + 2] + wv.w * h1s[qq + 3];
  }
  float t1 = acc, t2 = acc * acc;
  #pragma unroll
  for (int m = 32; m; m >>= 1) { t1 += __shfl_xor(t1, m); t2 += __shfl_xor(t2, m); }
  if (lane == 0) { red[w] = t1; red[4 + w] = t2; }
  __syncthreads();
  float T1 = red[0] + red[1] + red[2] + red[3];
  float T2 = red[4] + red[5] + red[6] + red[7];
  float m2 = T1 * (1.f / 256.f);
  float v2 = T2 * (1.f / 256.f) - m2 * m2;
  float rs2 = rsqrtf(v2 + EPS);
  float h2 = (acc - m2) * rs2 * n2_g[tid] + n2_b[tid];
  h2 = h2 >= 0.f ? h2 : 0.2f * h2;
  float lg = h2 * w2[tid];
  #pragma unroll
  for (int m = 32; m; m >>= 1) lg += __shfl_xor(lg, m);
  __syncthreads();
  if (lane == 0) red[w] = lg;
  __syncthreads();
  if (tid == 0) dout[b] = red[0] + red[1] + red[2] + red[3] + b2[0];
}

extern "C" void kernel_launch(void* const* d_in, const int* in_sizes, int n_in,
                              void* d_out, int out_size, void* d_ws, size_t ws_size,
                              hipStream_t stream)
{
  const float* img     = (const float*)d_in[0];
  const float* pathway = (const float*)d_in[1];
  const float* qw      = (const float*)d_in[2];
  const float* qw2     = (const float*)d_in[3];
  const float* kw      = (const float*)d_in[4];
  const float* vw      = (const float*)d_in[5];
  const float* vw2     = (const float*)d_in[6];
  const float* q_g     = (const float*)d_in[7];
  const float* q_b     = (const float*)d_in[8];
  const float* k_g     = (const float*)d_in[9];
  const float* k_b     = (const float*)d_in[10];
  const float* v_g     = (const float*)d_in[11];
  const float* v_b     = (const float*)d_in[12];
  const float* n1_g    = (const float*)d_in[13];
  const float* n1_b    = (const float*)d_in[14];
  const float* n2_g    = (const float*)d_in[15];
  const float* n2_b    = (const float*)d_in[16];
  const float* w1      = (const float*)d_in[17];
  const float* b1      = (const float*)d_in[18];
  const float* w2      = (const float*)d_in[19];
  const float* b2      = (const float*)d_in[20];
  float* dout = (float*)d_out;

  // workspace layout (bytes): qm bf16 [32*2048*64] @0 ; km bf16 [32*4096*64] @8MB ; vm f32 [32*4096] @24MB
  unsigned short* qm_ws = (unsigned short*)d_ws;
  unsigned short* km_ws = (unsigned short*)((char*)d_ws + 8388608);
  float*          vm_ws = (float*)((char*)d_ws + 25165824);

  k_qm<<<dim3(2048), dim3(256), 0, stream>>>(pathway, qw, qw2, q_g, q_b, qm_ws);
  k_kmvm<<<dim3(32768), dim3(256), 0, stream>>>(img, kw, vw, vw2, k_g, k_b, v_g, v_b, km_ws, vm_ws);
  k_attn<<<dim3(1024), dim3(256), 0, stream>>>(qm_ws, km_ws, vm_ws, dout);
  k_head<<<dim3(32), dim3(256), 0, stream>>>(n1_g, n1_b, n2_g, n2_b, w1, b1, w2, b2, dout);
}

// Round 12
// 406.752 us; speedup vs baseline: 1.9001x; 1.9001x over previous
//
#include <hip/hip_runtime.h>
#include <hip/hip_bf16.h>

#define EPS 1e-5f
#define INV_VRF 4.4194173824159220e-02f  // 2/sqrt(2048)

#define NB 32
#define NP 2048
#define NI 4096
#define ND 64
#define NL 256

#define ATTN_OFF 32L
#define OUT_OFF  268435488L  // 32 + 32*2048*4096

typedef __attribute__((ext_vector_type(4))) float vf4;
typedef __attribute__((ext_vector_type(8))) short vs8;

__device__ __forceinline__ unsigned short f2bf(float f) {
  unsigned int u = __float_as_uint(f);
  unsigned int r = (u + 0x7FFFu + ((u >> 16) & 1u)) >> 16;
  return (unsigned short)r;
}

// permute k-index d (0..63) into MFMA-fragment element order, so a frag for
// (kk, g) is the contiguous 16B at element [kk*32 + g*8 .. +8).
__device__ __forceinline__ int kperm(int d) {
  int dd = d & 31;
  return (d & 32) + (((dd & 15) >> 2) << 3) + ((dd >> 4) << 2) + (dd & 3);
}

// ---------------- K1: qm = lrelu( lrelu(LN(s*qw)) @ qw2 ), bf16 (permuted cols) ----------------
__global__ __launch_bounds__(256) void k_qm(
    const float* __restrict__ pathway, const float* __restrict__ qw,
    const float* __restrict__ qw2, const float* __restrict__ q_g,
    const float* __restrict__ q_b, unsigned short* __restrict__ qm)
{
  __shared__ float qw2s[64 * 64];
  int tid = threadIdx.x, lane = tid & 63, w = tid >> 6;
  for (int idx = tid; idx < 4096; idx += 256) qw2s[idx] = qw2[idx];
  float qwv = qw[lane], qg = q_g[lane], qb = q_b[lane];
  float s1 = qwv, s2 = qwv * qwv;
  #pragma unroll
  for (int m = 32; m; m >>= 1) { s1 += __shfl_xor(s1, m); s2 += __shfl_xor(s2, m); }
  float mq = s1 * (1.f / 64.f), vq = s2 * (1.f / 64.f) - mq * mq;
  float qc = qwv - mq;
  int pdst = kperm(lane);
  __syncthreads();
  long base = (long)blockIdx.x * 32 + w * 8;
  for (int r = 0; r < 8; ++r) {
    long row = base + r;
    float s = pathway[row];
    float alpha = s * rsqrtf(s * s * vq + EPS);
    float t = alpha * qc * qg + qb;
    t = t >= 0.f ? t : 0.2f * t;
    float acc = 0.f;
    #pragma unroll
    for (int h = 0; h < 64; ++h) acc += __shfl(t, h) * qw2s[h * 64 + lane];
    acc = acc >= 0.f ? acc : 0.2f * acc;
    qm[row * 64 + pdst] = f2bf(acc);
  }
}

// ---------------- K2: km = LN(img_t@kw) bf16 (permuted cols) ; vm = lrelu(LN(img_t@vw))@vw2 ----------------
// 2048 blocks x 64 rows, img staged in LDS (coalesced), weights preloaded.
__global__ __launch_bounds__(256) void k_kmvm(
    const float* __restrict__ img, const float* __restrict__ kw,
    const float* __restrict__ vw, const float* __restrict__ vw2,
    const float* __restrict__ k_g, const float* __restrict__ k_b,
    const float* __restrict__ v_g, const float* __restrict__ v_b,
    unsigned short* __restrict__ km, float* __restrict__ vm)
{
  __shared__ float imgs[4][64];
  int tid = threadIdx.x, lane = tid & 63, w = tid >> 6;
  int bid = blockIdx.x;
  long row0 = (long)bid * 64;
  int b = (int)(row0 >> 12), i0 = (int)(row0 & 4095);
  { int j = tid >> 6, ii = tid & 63;
    imgs[j][ii] = img[(long)b * 16384 + j * 4096 + i0 + ii]; }
  int d = lane;
  float kw0 = kw[d], kw1 = kw[64 + d], kw2 = kw[128 + d], kw3 = kw[192 + d];
  float vw0 = vw[d], vw1 = vw[64 + d], vw2_ = vw[128 + d], vw3 = vw[192 + d];
  float kg = k_g[d], kbb = k_b[d], vg = v_g[d], vb = v_b[d], vw2d = vw2[d];
  int pd = kperm(d);
  __syncthreads();
  for (int r = 0; r < 16; ++r) {
    int ii = w * 16 + r;
    long row = row0 + ii;
    float x0 = imgs[0][ii], x1 = imgs[1][ii], x2 = imgs[2][ii], x3 = imgs[3][ii];
    float kp = x0 * kw0 + x1 * kw1 + x2 * kw2 + x3 * kw3;
    float vp = x0 * vw0 + x1 * vw1 + x2 * vw2_ + x3 * vw3;
    float a1 = kp, a2 = kp * kp, a3 = vp, a4 = vp * vp;
    #pragma unroll
    for (int m = 32; m; m >>= 1) {
      a1 += __shfl_xor(a1, m); a2 += __shfl_xor(a2, m);
      a3 += __shfl_xor(a3, m); a4 += __shfl_xor(a4, m);
    }
    float mk = a1 * (1.f / 64.f), vk = a2 * (1.f / 64.f) - mk * mk;
    float mv = a3 * (1.f / 64.f), vv = a4 * (1.f / 64.f) - mv * mv;
    float kmv = (kp - mk) * rsqrtf(vk + EPS) * kg + kbb;
    km[row * 64 + pd] = f2bf(kmv);
    float y = (vp - mv) * rsqrtf(vv + EPS) * vg + vb;
    y = y >= 0.f ? y : 0.2f * y;
    float pv = y * vw2d;
    #pragma unroll
    for (int m = 32; m; m >>= 1) pv += __shfl_xor(pv, m);
    if (lane == 0) vm[row] = pv;
  }
}

// ---------------- K_tr: w1 [256][2048] -> w1t [2048][256] (LDS tile transpose) ----------------
__global__ __launch_bounds__(256) void k_tr(
    const float* __restrict__ w1, float* __restrict__ w1t)
{
  __shared__ float lds[64][65];
  int tid = threadIdx.x;
  int bid = blockIdx.x;           // 128 blocks = 32 qt x 4 jt
  int qt = bid >> 2, jt = bid & 3;
  #pragma unroll
  for (int it = 0; it < 16; ++it) {
    int jl = it * 4 + (tid >> 6), ql = tid & 63;
    lds[jl][ql] = w1[(long)(jt * 64 + jl) * 2048 + qt * 64 + ql];
  }
  __syncthreads();
  #pragma unroll
  for (int it = 0; it < 16; ++it) {
    int ql = it * 4 + (tid >> 6), jl = tid & 63;
    w1t[(long)(qt * 64 + ql) * 256 + jt * 64 + jl] = lds[jl][ql];
  }
}

// ---------------- K3: attn = softsign(relu(qm@km^T)/vrf) -> d_out ; out = attn@vm ----------------
// R2 structure verbatim (best known: NT stores, direct L2 km reads, no barriers).
__global__ __launch_bounds__(256) void k_attn(
    const unsigned short* __restrict__ qm, const unsigned short* __restrict__ km,
    const float* __restrict__ vm, float* __restrict__ dout)
{
  __shared__ __align__(16) float tr_s[4][16 * 128];  // per-wave 16x128 f32, f4-XOR swizzled
  int tid = threadIdx.x, lane = tid & 63, w = tid >> 6;
  int g = lane >> 4, c = lane & 15;
  // XCD swizzle: blocks sharing b land on one XCD (1024 = 8 xcd * 128)
  int bid = blockIdx.x;
  int lbid = (bid & 7) * 128 + (bid >> 3);
  int b = lbid >> 5, pt = lbid & 31;
  long p_base = (long)b * NP + pt * 64;
  int prow = w * 16;

  // A fragments: rows p_base+prow+c, permuted element order -> one vs8 load per half
  const unsigned short* qrow = qm + (p_base + prow + c) * 64;
  vs8 afr0 = *(const vs8*)(qrow + g * 8);
  vs8 afr1 = *(const vs8*)(qrow + 32 + g * 8);

  const unsigned short* kb = km + (long)b * NI * 64;
  const float* vmb = vm + (long)b * NI;
  float* trw = tr_s[w];
  float* outbase = dout + ATTN_OFF + (p_base + prow) * (long)NI;
  float oacc[4] = {0.f, 0.f, 0.f, 0.f};

  for (int s = 0; s < 32; ++s) {
    int i0 = s * 128;
    vf4 acc[8];
    #pragma unroll
    for (int nt = 0; nt < 8; ++nt) acc[nt] = (vf4){0.f, 0.f, 0.f, 0.f};
    #pragma unroll
    for (int nt = 0; nt < 8; ++nt) {
      const unsigned short* krow = kb + (long)(i0 + nt * 16 + c) * 64;
      vs8 b0 = *(const vs8*)(krow + g * 8);
      vs8 b1 = *(const vs8*)(krow + 32 + g * 8);
      acc[nt] = __builtin_amdgcn_mfma_f32_16x16x32_bf16(afr0, b0, acc[nt], 0, 0, 0);
      acc[nt] = __builtin_amdgcn_mfma_f32_16x16x32_bf16(afr1, b1, acc[nt], 0, 0, 0);
    }
    // softsign + transpose write (XOR-swizzled f4 slots)
    #pragma unroll
    for (int nt = 0; nt < 8; ++nt) {
      #pragma unroll
      for (int r = 0; r < 4; ++r) {
        float x = fmaxf(acc[nt][r], 0.f) * INV_VRF;
        float y = x * __builtin_amdgcn_rcpf(x + 0.5f);
        int row = g * 4 + r;                 // 0..15
        int f4 = (nt * 4 + (c >> 2)) ^ row;  // 0..31, low-4-bit XOR
        trw[row * 128 + f4 * 4 + (c & 3)] = y;
      }
    }
    // transpose read + coalesced NT stores: per instr 4 rows x 256B contiguous
    #pragma unroll
    for (int pass = 0; pass < 2; ++pass) {
      vf4 vmv = *(const vf4*)(vmb + i0 + pass * 64 + c * 4);
      #pragma unroll
      for (int j = 0; j < 4; ++j) {
        int row = j * 4 + g;
        int f4 = (pass * 16 + c) ^ row;
        vf4 yv = *(const vf4*)&trw[row * 128 + f4 * 4];
        __builtin_nontemporal_store(
            yv, (vf4*)(outbase + (long)row * NI + i0 + pass * 64 + c * 4));
        oacc[j] += yv[0] * vmv[0] + yv[1] * vmv[1] + yv[2] * vmv[2] + yv[3] * vmv[3];
      }
    }
  }
  // reduce oacc over the 16 c-lanes within each g-group
  #pragma unroll
  for (int m = 1; m <= 8; m <<= 1) {
    #pragma unroll
    for (int j = 0; j < 4; ++j) oacc[j] += __shfl_xor(oacc[j], m);
  }
  if (c == 0) {
    #pragma unroll
    for (int j = 0; j < 4; ++j)
      dout[OUT_OFF + p_base + prow + j * 4 + g] = oacc[j];
  }
}

// ---------------- K4: classifier head (coalesced w1t matvec, wave-split q) ----------------
__global__ __launch_bounds__(256) void k_head(
    const float* __restrict__ w1t,
    const float* __restrict__ n1_g, const float* __restrict__ n1_b,
    const float* __restrict__ n2_g, const float* __restrict__ n2_b,
    const float* __restrict__ b1,
    const float* __restrict__ w2, const float* __restrict__ b2,
    float* __restrict__ dout)
{
  int tid = threadIdx.x, lane = tid & 63, w = tid >> 6;
  int b = blockIdx.x;
  __shared__ float h1s[2048];
  __shared__ float part[4][256];
  __shared__ float red[8];
  const float* orow = dout + OUT_OFF + (long)b * NP;
  float vals[8];
  float s1 = 0.f, s2 = 0.f;
  #pragma unroll
  for (int j = 0; j < 8; ++j) {
    float v = orow[j * 256 + tid];
    vals[j] = v; s1 += v; s2 += v * v;
  }
  #pragma unroll
  for (int m = 32; m; m >>= 1) { s1 += __shfl_xor(s1, m); s2 += __shfl_xor(s2, m); }
  if (lane == 0) { red[w] = s1; red[4 + w] = s2; }
  __syncthreads();
  float S1 = red[0] + red[1] + red[2] + red[3];
  float S2 = red[4] + red[5] + red[6] + red[7];
  float mean = S1 * (1.f / 2048.f);
  float var = S2 * (1.f / 2048.f) - mean * mean;
  float rs = rsqrtf(var + EPS);
  __syncthreads();
  #pragma unroll
  for (int j = 0; j < 8; ++j) {
    int p = j * 256 + tid;
    float h = (vals[j] - mean) * rs * n1_g[p] + n1_b[p];
    h = h >= 0.f ? h : 0.2f * h;
    h1s[p] = h;
  }
  __syncthreads();
  // wave-split matvec: wave w covers q in [w*512, w*512+512); lane handles outputs 4l..4l+3
  {
    const float* wp = w1t + (long)(w * 512) * 256 + lane * 4;
    const float* hp = h1s + w * 512;
    float a0 = 0.f, a1 = 0.f, a2 = 0.f, a3 = 0.f;
    for (int q = 0; q < 512; ++q) {
      float v = hp[q];
      vf4 wv = *(const vf4*)(wp + q * 256);
      a0 += v * wv[0]; a1 += v * wv[1]; a2 += v * wv[2]; a3 += v * wv[3];
    }
    part[w][lane * 4 + 0] = a0; part[w][lane * 4 + 1] = a1;
    part[w][lane * 4 + 2] = a2; part[w][lane * 4 + 3] = a3;
  }
  __syncthreads();
  float acc = part[0][tid] + part[1][tid] + part[2][tid] + part[3][tid] + b1[tid];
  float t1 = acc, t2 = acc * acc;
  #pragma unroll
  for (int m = 32; m; m >>= 1) { t1 += __shfl_xor(t1, m); t2 += __shfl_xor(t2, m); }
  __syncthreads();
  if (lane == 0) { red[w] = t1; red[4 + w] = t2; }
  __syncthreads();
  float T1 = red[0] + red[1] + red[2] + red[3];
  float T2 = red[4] + red[5] + red[6] + red[7];
  float m2 = T1 * (1.f / 256.f);
  float v2 = T2 * (1.f / 256.f) - m2 * m2;
  float rs2 = rsqrtf(v2 + EPS);
  float h2 = (acc - m2) * rs2 * n2_g[tid] + n2_b[tid];
  h2 = h2 >= 0.f ? h2 : 0.2f * h2;
  float lg = h2 * w2[tid];
  #pragma unroll
  for (int m = 32; m; m >>= 1) lg += __shfl_xor(lg, m);
  __syncthreads();
  if (lane == 0) red[w] = lg;
  __syncthreads();
  if (tid == 0) dout[b] = red[0] + red[1] + red[2] + red[3] + b2[0];
}

extern "C" void kernel_launch(void* const* d_in, const int* in_sizes, int n_in,
                              void* d_out, int out_size, void* d_ws, size_t ws_size,
                              hipStream_t stream)
{
  const float* img     = (const float*)d_in[0];
  const float* pathway = (const float*)d_in[1];
  const float* qw      = (const float*)d_in[2];
  const float* qw2     = (const float*)d_in[3];
  const float* kw      = (const float*)d_in[4];
  const float* vw      = (const float*)d_in[5];
  const float* vw2     = (const float*)d_in[6];
  const float* q_g     = (const float*)d_in[7];
  const float* q_b     = (const float*)d_in[8];
  const float* k_g     = (const float*)d_in[9];
  const float* k_b     = (const float*)d_in[10];
  const float* v_g     = (const float*)d_in[11];
  const float* v_b     = (const float*)d_in[12];
  const float* n1_g    = (const float*)d_in[13];
  const float* n1_b    = (const float*)d_in[14];
  const float* n2_g    = (const float*)d_in[15];
  const float* n2_b    = (const float*)d_in[16];
  const float* w1      = (const float*)d_in[17];
  const float* b1      = (const float*)d_in[18];
  const float* w2      = (const float*)d_in[19];
  const float* b2      = (const float*)d_in[20];
  float* dout = (float*)d_out;

  // ws layout (bytes): qm bf16 @0 (8MB); km bf16 @8MB (16MB); vm f32 @24MB (512KB); w1t f32 @24.5MB (2MB)
  unsigned short* qm_ws  = (unsigned short*)d_ws;
  unsigned short* km_ws  = (unsigned short*)((char*)d_ws + 8388608);
  float*          vm_ws  = (float*)((char*)d_ws + 25165824);
  float*          w1t_ws = (float*)((char*)d_ws + 25690112);

  k_qm<<<dim3(2048), dim3(256), 0, stream>>>(pathway, qw, qw2, q_g, q_b, qm_ws);
  k_kmvm<<<dim3(2048), dim3(256), 0, stream>>>(img, kw, vw, vw2, k_g, k_b, v_g, v_b, km_ws, vm_ws);
  k_tr<<<dim3(128), dim3(256), 0, stream>>>(w1, w1t_ws);
  k_attn<<<dim3(1024), dim3(256), 0, stream>>>(qm_ws, km_ws, vm_ws, dout);
  k_head<<<dim3(32), dim3(256), 0, stream>>>(w1t_ws, n1_g, n1_b, n2_g, n2_b, b1, w2, b2, dout);
}